// Round 2
// baseline (1143.914 us; speedup 1.0000x reference)
//
#include <hip/hip_runtime.h>
#include <cstdint>
#include <cstddef>

using u16 = unsigned short;
using u32 = unsigned int;

#define DI __device__ __forceinline__

// bf16 <-> f32 helpers (bit math). Intermediates are stored bf16 in ws.
DI float bfu2f(u16 u) { return __uint_as_float(((u32)u) << 16); }
DI u16 f2bu(float f) {  // round-to-nearest-even, finite inputs only
    u32 x = __float_as_uint(f);
    return (u16)((x + 0x7fffu + ((x >> 16) & 1u)) >> 16);
}

constexpr int CIN = 512;
constexpr int HW  = 4096;              // 64*64
constexpr size_t PLANE = 16777216ull;  // 8*512*4096 elements per output tensor

// ======================= 1x1-conv projection GEMM =======================
// Out[b] (Co x 4096) = Wm (Co x 512) @ X[b] (512 x 4096) + bias.
// f32 inputs, bf16 output (ws). grid (HW/64, Co/64, B), block 256.
__global__ __launch_bounds__(256) void proj_gemm(
    const float* __restrict__ X, const float* __restrict__ Wm,
    const float* __restrict__ bias, u16* __restrict__ Out, int Co)
{
    __shared__ float Wt[32][68];  // [kk][m]; 68 keeps float4 rows 16B-aligned
    __shared__ float Xt[32][68];  // [kk][n]
    const int b  = blockIdx.z;
    const int m0 = blockIdx.y * 64;
    const int n0 = blockIdx.x * 64;
    const int tid = threadIdx.x;
    const int tx = tid & 15, ty = tid >> 4;
    const float* Xb = X + (size_t)b * CIN * HW;
    const int wm = tid >> 2, wk0 = (tid & 3) * 8;  // W stage: 8 f32/thread
    const int xk = tid >> 3, xn0 = (tid & 7) * 8;  // X stage: 8 f32/thread
    float acc[4][4] = {};
    for (int k0 = 0; k0 < CIN; k0 += 32) {
        const float* wp = Wm + (size_t)(m0 + wm) * CIN + k0 + wk0;
        float4 w0 = *reinterpret_cast<const float4*>(wp);
        float4 w1 = *reinterpret_cast<const float4*>(wp + 4);
        const float* xp = Xb + (size_t)(k0 + xk) * HW + n0 + xn0;
        float4 r0 = *reinterpret_cast<const float4*>(xp);
        float4 r1 = *reinterpret_cast<const float4*>(xp + 4);
        Wt[wk0 + 0][wm] = w0.x; Wt[wk0 + 1][wm] = w0.y;
        Wt[wk0 + 2][wm] = w0.z; Wt[wk0 + 3][wm] = w0.w;
        Wt[wk0 + 4][wm] = w1.x; Wt[wk0 + 5][wm] = w1.y;
        Wt[wk0 + 6][wm] = w1.z; Wt[wk0 + 7][wm] = w1.w;
        *reinterpret_cast<float4*>(&Xt[xk][xn0])     = r0;
        *reinterpret_cast<float4*>(&Xt[xk][xn0 + 4]) = r1;
        __syncthreads();
        #pragma unroll 8
        for (int kk = 0; kk < 32; kk++) {
            float4 av = *reinterpret_cast<const float4*>(&Wt[kk][ty * 4]);
            float4 bv = *reinterpret_cast<const float4*>(&Xt[kk][tx * 4]);
            float a[4] = {av.x, av.y, av.z, av.w};
            float c[4] = {bv.x, bv.y, bv.z, bv.w};
            #pragma unroll
            for (int i = 0; i < 4; i++)
                #pragma unroll
                for (int j = 0; j < 4; j++) acc[i][j] += a[i] * c[j];
        }
        __syncthreads();
    }
    #pragma unroll
    for (int i = 0; i < 4; i++) {
        int m = m0 + ty * 4 + i;
        float bv = bias[m];
        u32 lo = (u32)f2bu(acc[i][0] + bv) | ((u32)f2bu(acc[i][1] + bv) << 16);
        u32 hi = (u32)f2bu(acc[i][2] + bv) | ((u32)f2bu(acc[i][3] + bv) << 16);
        *reinterpret_cast<uint2*>(Out + ((size_t)b * Co + m) * HW + n0 + tx * 4) = make_uint2(lo, hi);
    }
}

// ============== 64x64 last-two-dims transpose (bf16 -> bf16) ==============
__global__ __launch_bounds__(256) void transpose64_bb(
    const u16* __restrict__ src, u16* __restrict__ dst)
{
    __shared__ u16 t[64][65];
    const size_t s = blockIdx.x;
    const u16* sp = src + s * 4096;
    u16* dp = dst + s * 4096;
    const int tid = threadIdx.x;
    #pragma unroll
    for (int i = 0; i < 16; i++) { int idx = tid + 256 * i; t[idx >> 6][idx & 63] = sp[idx]; }
    __syncthreads();
    #pragma unroll
    for (int i = 0; i < 16; i++) { int idx = tid + 256 * i; dp[idx] = t[idx & 63][idx >> 6]; }
}

// ======================= energies =======================
// e layout: (b,h,w,128) fp32. [0:64) = energy_H, [64:128) = energy_W.
__global__ __launch_bounds__(256) void energy_h(
    const u16* __restrict__ qT, const u16* __restrict__ kT, float* __restrict__ e)
{
    __shared__ float Qs[64][68];  // [c][h]
    __shared__ float Ks[64][68];  // [c][H']
    const int w = blockIdx.x, b = blockIdx.y;
    const int tid = threadIdx.x;
    const size_t base = (size_t)b * 64 * HW + (size_t)w * 64;  // qT[b,c,w,h]
    #pragma unroll
    for (int i = 0; i < 16; i++) {
        int idx = tid + 256 * i;
        int c = idx >> 6, x = idx & 63;
        Qs[c][x] = bfu2f(qT[base + (size_t)c * HW + x]);
        Ks[c][x] = bfu2f(kT[base + (size_t)c * HW + x]);
    }
    __syncthreads();
    const int tx = tid & 15, ty = tid >> 4;  // tx -> h, ty -> H'
    float acc[4][4] = {};
    #pragma unroll 8
    for (int c = 0; c < 64; c++) {
        float4 qv = *reinterpret_cast<const float4*>(&Qs[c][tx * 4]);
        float4 kv = *reinterpret_cast<const float4*>(&Ks[c][ty * 4]);
        float a[4] = {qv.x, qv.y, qv.z, qv.w};
        float d[4] = {kv.x, kv.y, kv.z, kv.w};
        #pragma unroll
        for (int i = 0; i < 4; i++)
            #pragma unroll
            for (int j = 0; j < 4; j++) acc[i][j] += a[i] * d[j];
    }
    #pragma unroll
    for (int i = 0; i < 4; i++) {
        float4 v = make_float4(acc[i][0], acc[i][1], acc[i][2], acc[i][3]);
        *reinterpret_cast<float4*>(e + ((size_t)(b * 64 + tx * 4 + i) * 64 + w) * 128 + ty * 4) = v;
    }
}

__global__ __launch_bounds__(256) void energy_w(
    const u16* __restrict__ q, const u16* __restrict__ k, float* __restrict__ e)
{
    __shared__ float Qs[64][68];  // [c][w]
    __shared__ float Ks[64][68];  // [c][W']
    const int h = blockIdx.x, b = blockIdx.y;
    const int tid = threadIdx.x;
    const size_t base = (size_t)b * 64 * HW + (size_t)h * 64;  // q[b,c,h,w]
    #pragma unroll
    for (int i = 0; i < 16; i++) {
        int idx = tid + 256 * i;
        int c = idx >> 6, x = idx & 63;
        Qs[c][x] = bfu2f(q[base + (size_t)c * HW + x]);
        Ks[c][x] = bfu2f(k[base + (size_t)c * HW + x]);
    }
    __syncthreads();
    const int tx = tid & 15, ty = tid >> 4;  // tx -> w, ty -> W'
    float acc[4][4] = {};
    #pragma unroll 8
    for (int c = 0; c < 64; c++) {
        float4 qv = *reinterpret_cast<const float4*>(&Qs[c][tx * 4]);
        float4 kv = *reinterpret_cast<const float4*>(&Ks[c][ty * 4]);
        float a[4] = {qv.x, qv.y, qv.z, qv.w};
        float d[4] = {kv.x, kv.y, kv.z, kv.w};
        #pragma unroll
        for (int i = 0; i < 4; i++)
            #pragma unroll
            for (int j = 0; j < 4; j++) acc[i][j] += a[i] * d[j];
    }
    #pragma unroll
    for (int i = 0; i < 4; i++) {
        float4 v = make_float4(acc[i][0], acc[i][1], acc[i][2], acc[i][3]);
        *reinterpret_cast<float4*>(e + ((size_t)(b * 64 + h) * 64 + tx * 4 + i) * 128 + 64 + ty * 4) = v;
    }
}

// ======================= softmax over 128, in place =======================
__global__ __launch_bounds__(256) void softmax128(float* __restrict__ e)
{
    const int pos = blockIdx.x * 4 + (threadIdx.x >> 6);
    const int l = threadIdx.x & 63;
    float* p = e + (size_t)pos * 128;
    float v0 = p[l], v1 = p[l + 64];
    float m = fmaxf(v0, v1);
    #pragma unroll
    for (int o = 32; o > 0; o >>= 1) m = fmaxf(m, __shfl_xor(m, o, 64));
    float e0 = __expf(v0 - m), e1 = __expf(v1 - m);
    float s = e0 + e1;
    #pragma unroll
    for (int o = 32; o > 0; o >>= 1) s += __shfl_xor(s, o, 64);
    float inv = 1.0f / s;
    p[l] = e0 * inv;
    p[l + 64] = e1 * inv;
}

// ======================= H-term aggregation =======================
// outH[b,c,h,w] = sum_H' v[b,c,H',w] * att_H[b,h,w,H'], written as f32
// partial directly into d_out at final addresses (scalar scatter stores).
__global__ __launch_bounds__(256) void agg_h(
    const u16* __restrict__ v2, const u16* __restrict__ v1,
    const float* __restrict__ att, float* __restrict__ outp)
{
    __shared__ float As[64][68];  // [H'][h]
    __shared__ float Vs[64][68];  // [H'][c]
    const int ct = blockIdx.x, w = blockIdx.y, b = blockIdx.z;
    const int tid = threadIdx.x;
    #pragma unroll
    for (int i = 0; i < 16; i++) {
        int idx = tid + 256 * i;
        int hh = idx >> 6, hp = idx & 63;
        As[hp][hh] = att[((size_t)(b * 64 + hh) * 64 + w) * 128 + hp];
    }
    const int tx = tid & 15, ty = tid >> 4;  // tx -> h, ty -> c
    const size_t vbase = (size_t)(b * 512 + ct * 64) * HW + w;  // + c*HW + hp*64
    for (int vs = 0; vs < 2; vs++) {
        const u16* v = vs ? v1 : v2;
        __syncthreads();
        #pragma unroll
        for (int i = 0; i < 16; i++) {
            int idx = tid + 256 * i;
            int c = idx >> 6, hp = idx & 63;  // stride-64 reads; L2-served
            Vs[hp][c] = bfu2f(v[vbase + (size_t)c * HW + (size_t)hp * 64]);
        }
        __syncthreads();
        float acc[4][4] = {};
        #pragma unroll 8
        for (int hp = 0; hp < 64; hp++) {
            float4 vv = *reinterpret_cast<const float4*>(&Vs[hp][ty * 4]);
            float4 aa = *reinterpret_cast<const float4*>(&As[hp][tx * 4]);
            float a[4] = {vv.x, vv.y, vv.z, vv.w};
            float d[4] = {aa.x, aa.y, aa.z, aa.w};
            #pragma unroll
            for (int i = 0; i < 4; i++)
                #pragma unroll
                for (int j = 0; j < 4; j++) acc[i][j] += a[i] * d[j];
        }
        float* po = outp + (size_t)vs * PLANE;
        #pragma unroll
        for (int i = 0; i < 4; i++)
            #pragma unroll
            for (int j = 0; j < 4; j++)
                po[(size_t)(b * 512 + ct * 64 + ty * 4 + i) * HW + (size_t)(tx * 4 + j) * 64 + w]
                    = acc[i][j];
    }
}

// ======================= W-term + epilogue =======================
// outW[b,c,h,w] = sum_W' v[b,c,h,W'] * att_W[b,h,w,W']
// y = g*(partialH + outW) + x, in place in d_out (f32).
__global__ __launch_bounds__(256) void agg_w(
    const u16* __restrict__ v2, const u16* __restrict__ v1,
    const float* __restrict__ att,
    const float* __restrict__ x2, const float* __restrict__ x1,
    const float* __restrict__ gptr, float* __restrict__ outp)
{
    __shared__ float As[64][68];  // [W'][w]
    __shared__ float Vs[64][68];  // [W'][c]
    const int ct = blockIdx.x, h = blockIdx.y, b = blockIdx.z;
    const int tid = threadIdx.x;
    #pragma unroll
    for (int i = 0; i < 16; i++) {
        int idx = tid + 256 * i;
        int ww = idx >> 6, wp = idx & 63;
        As[wp][ww] = att[((size_t)(b * 64 + h) * 64 + ww) * 128 + 64 + wp];
    }
    const float g = gptr[0];
    const int tx = tid & 15, ty = tid >> 4;  // tx -> w, ty -> c
    const size_t vbase = (size_t)(b * 512 + ct * 64) * HW + (size_t)h * 64;
    for (int vs = 0; vs < 2; vs++) {
        const u16* v = vs ? v1 : v2;
        const float* x = vs ? x1 : x2;
        float* po = outp + (size_t)vs * PLANE;
        __syncthreads();
        #pragma unroll
        for (int i = 0; i < 16; i++) {
            int idx = tid + 256 * i;
            int c = idx >> 6, wp = idx & 63;  // coalesced
            Vs[wp][c] = bfu2f(v[vbase + (size_t)c * HW + wp]);
        }
        __syncthreads();
        float acc[4][4] = {};
        #pragma unroll 8
        for (int wp = 0; wp < 64; wp++) {
            float4 vv = *reinterpret_cast<const float4*>(&Vs[wp][ty * 4]);
            float4 aa = *reinterpret_cast<const float4*>(&As[wp][tx * 4]);
            float a[4] = {vv.x, vv.y, vv.z, vv.w};
            float d[4] = {aa.x, aa.y, aa.z, aa.w};
            #pragma unroll
            for (int i = 0; i < 4; i++)
                #pragma unroll
                for (int j = 0; j < 4; j++) acc[i][j] += a[i] * d[j];
        }
        #pragma unroll
        for (int i = 0; i < 4; i++) {
            size_t off = (size_t)(b * 512 + ct * 64 + ty * 4 + i) * HW + (size_t)h * 64 + tx * 4;
            float4 pv = *reinterpret_cast<const float4*>(po + off);
            float4 xv = *reinterpret_cast<const float4*>(x + off);
            float4 y;
            y.x = g * (pv.x + acc[i][0]) + xv.x;
            y.y = g * (pv.y + acc[i][1]) + xv.y;
            y.z = g * (pv.z + acc[i][2]) + xv.z;
            y.w = g * (pv.w + acc[i][3]) + xv.w;
            *reinterpret_cast<float4*>(po + off) = y;
        }
    }
}

// ======================= host =======================
extern "C" void kernel_launch(void* const* d_in, const int* in_sizes, int n_in,
                              void* d_out, int out_size, void* d_ws, size_t ws_size,
                              hipStream_t stream)
{
    (void)in_sizes; (void)n_in; (void)out_size; (void)ws_size;
    const float* x2  = (const float*)d_in[0];
    const float* x1  = (const float*)d_in[1];
    const float* q_w = (const float*)d_in[2];
    const float* q_b = (const float*)d_in[3];
    const float* k_w = (const float*)d_in[4];
    const float* k_b = (const float*)d_in[5];
    const float* v_w = (const float*)d_in[6];
    const float* v_b = (const float*)d_in[7];
    const float* gm  = (const float*)d_in[8];

    // ws layout (MiB): q 0-4 | k 4-8 | qT 8-12 | kT 12-16 | e(f32) 16-32
    //                  v2 32-64 | v1 64-96       (total 96 MiB)
    char* ws = (char*)d_ws;
    u16*   q  = (u16*)(ws);
    u16*   k  = (u16*)(ws + ((size_t)4  << 20));
    u16*   qT = (u16*)(ws + ((size_t)8  << 20));
    u16*   kT = (u16*)(ws + ((size_t)12 << 20));
    float* e  = (float*)(ws + ((size_t)16 << 20));
    u16*   v2 = (u16*)(ws + ((size_t)32 << 20));
    u16*   v1 = (u16*)(ws + ((size_t)64 << 20));
    float* out = (float*)d_out;

    dim3 blk(256);
    proj_gemm<<<dim3(64, 1, 8), blk, 0, stream>>>(x2, q_w, q_b, q, 64);
    proj_gemm<<<dim3(64, 1, 8), blk, 0, stream>>>(x2, k_w, k_b, k, 64);
    proj_gemm<<<dim3(64, 8, 8), blk, 0, stream>>>(x2, v_w, v_b, v2, 512);
    proj_gemm<<<dim3(64, 8, 8), blk, 0, stream>>>(x1, v_w, v_b, v1, 512);
    transpose64_bb<<<1024, blk, 0, stream>>>(q, qT);  // q+k contiguous -> qT+kT
    energy_h<<<dim3(64, 8), blk, 0, stream>>>(qT, kT, e);
    energy_w<<<dim3(64, 8), blk, 0, stream>>>(q, k, e);
    softmax128<<<8192, blk, 0, stream>>>(e);
    agg_h<<<dim3(8, 64, 8), blk, 0, stream>>>(v2, v1, e, out);
    agg_w<<<dim3(8, 64, 8), blk, 0, stream>>>(v2, v1, e, x2, x1, gm, out);
}

// Round 3
// 568.476 us; speedup vs baseline: 2.0122x; 2.0122x over previous
//
#include <hip/hip_runtime.h>
#include <cstdint>
#include <cstddef>

using u16 = unsigned short;
using u32 = unsigned int;

#define DI __device__ __forceinline__

typedef __attribute__((ext_vector_type(8))) short bf16x8;
typedef __attribute__((ext_vector_type(4))) float f32x4;

// bf16 <-> f32 helpers (bit math). Intermediates stored bf16 in ws.
DI float bfu2f(u16 u) { return __uint_as_float(((u32)u) << 16); }
DI u16 f2bu(float f) {  // round-to-nearest-even, finite inputs only
    u32 x = __float_as_uint(f);
    return (u16)((x + 0x7fffu + ((x >> 16) & 1u)) >> 16);
}
DI u32 pk2(float a, float b) { return (u32)f2bu(a) | ((u32)f2bu(b) << 16); }

constexpr int CIN = 512;
constexpr int HW  = 4096;              // 64*64
constexpr size_t PLANE = 16777216ull;  // 8*512*4096 elements per output tensor

// ================= MFMA projection GEMM =================
// Out[M x 32768] = Wcat[M x 512] @ X[512 x (b,4096)] + bias; bf16 out.
// Row routing: [0,n0r) -> w0/o0, [n0r,n0r+n1r) -> w1/o1, rest -> w2/o2.
// grid (nTiles=256, mTiles=M/128), block 256 (4 waves), 128x128 tile, BK=32.
__global__ __launch_bounds__(256) void proj_mfma(
    const float* __restrict__ X,
    const float* __restrict__ w0, const float* __restrict__ b0, int n0r,
    const float* __restrict__ w1, const float* __restrict__ b1, int n1r,
    const float* __restrict__ w2, const float* __restrict__ b2,
    u16* __restrict__ o0, u16* __restrict__ o1, u16* __restrict__ o2,
    int o0c, int o1c, int o2c)
{
    __shared__ u16 Wlds[128][40];   // [m][k], rows 80 B (16B-aligned b128)
    __shared__ u16 Xlds[32][136];   // [k][n], rows 272 B (2-way-max banks)
    const int tid = threadIdx.x;
    const int m0  = blockIdx.y * 128;
    const int n0g = blockIdx.x * 128;
    const int b    = n0g >> 12;
    const int col0 = n0g & 4095;
    const float* Xb = X + (size_t)b * CIN * HW;

    // staging coords
    const int ml = tid >> 1, wk0 = (tid & 1) * 16;   // W: 16 f32/thread
    const int xk = tid >> 3, xnb = (tid & 7) * 16;   // X: 16 f32/thread
    const int mrow = m0 + ml;
    const float* wr = (mrow < n0r) ? w0 + (size_t)mrow * CIN
                    : (mrow < n0r + n1r) ? w1 + (size_t)(mrow - n0r) * CIN
                    : w2 + (size_t)(mrow - n0r - n1r) * CIN;

    const int lane = tid & 63, wv = tid >> 6;
    const int wm = (wv & 1) * 64, wn = (wv >> 1) * 64;
    const int lr = lane & 15, lq = lane >> 4;

    f32x4 acc[4][4] = {};
    for (int kt = 0; kt < CIN; kt += 32) {
        // stage W (f32 -> bf16)
        {
            const float* p = wr + kt + wk0;
            float4 f0 = *(const float4*)(p);
            float4 f1 = *(const float4*)(p + 4);
            float4 f2 = *(const float4*)(p + 8);
            float4 f3 = *(const float4*)(p + 12);
            uint4 u0 = { pk2(f0.x, f0.y), pk2(f0.z, f0.w), pk2(f1.x, f1.y), pk2(f1.z, f1.w) };
            uint4 u1 = { pk2(f2.x, f2.y), pk2(f2.z, f2.w), pk2(f3.x, f3.y), pk2(f3.z, f3.w) };
            *(uint4*)&Wlds[ml][wk0]     = u0;
            *(uint4*)&Wlds[ml][wk0 + 8] = u1;
        }
        // stage X (f32 -> bf16), natural [k][n]
        {
            const float* p = Xb + (size_t)(kt + xk) * HW + col0 + xnb;
            float4 f0 = *(const float4*)(p);
            float4 f1 = *(const float4*)(p + 4);
            float4 f2 = *(const float4*)(p + 8);
            float4 f3 = *(const float4*)(p + 12);
            uint4 u0 = { pk2(f0.x, f0.y), pk2(f0.z, f0.w), pk2(f1.x, f1.y), pk2(f1.z, f1.w) };
            uint4 u1 = { pk2(f2.x, f2.y), pk2(f2.z, f2.w), pk2(f3.x, f3.y), pk2(f3.z, f3.w) };
            *(uint4*)&Xlds[xk][xnb]     = u0;
            *(uint4*)&Xlds[xk][xnb + 8] = u1;
        }
        __syncthreads();
        // A-frags: lane holds A[m=lr][k=lq*8+j] -> b128 from Wlds
        bf16x8 a[4];
        #pragma unroll
        for (int i = 0; i < 4; i++)
            a[i] = *(const bf16x8*)&Wlds[wm + i * 16 + lr][lq * 8];
        // B-frags: lane holds B[k=lq*8+j][n=lr] -> 8 scalar reads from Xlds
        #pragma unroll
        for (int j = 0; j < 4; j++) {
            bf16x8 bv;
            const int nn = wn + j * 16 + lr;
            #pragma unroll
            for (int jj = 0; jj < 8; jj++) bv[jj] = (short)Xlds[lq * 8 + jj][nn];
            #pragma unroll
            for (int i = 0; i < 4; i++)
                acc[i][j] = __builtin_amdgcn_mfma_f32_16x16x32_bf16(a[i], bv, acc[i][j], 0, 0, 0);
        }
        __syncthreads();
    }
    // epilogue: D row = lq*4 + r, col = lr. Route per 16-row frag (uniform).
    #pragma unroll
    for (int i = 0; i < 4; i++) {
        const int mbase = m0 + wm + i * 16;
        const float* bp; u16* op; int ch0, cc;
        if (mbase < n0r)             { bp = b0; op = o0; ch0 = mbase;             cc = o0c; }
        else if (mbase < n0r + n1r)  { bp = b1; op = o1; ch0 = mbase - n0r;       cc = o1c; }
        else                         { bp = b2; op = o2; ch0 = mbase - n0r - n1r; cc = o2c; }
        #pragma unroll
        for (int r = 0; r < 4; r++) {
            const int ch = ch0 + lq * 4 + r;
            const float bias = bp[ch];
            #pragma unroll
            for (int j = 0; j < 4; j++) {
                const int colx = col0 + wn + j * 16 + lr;
                op[((size_t)b * cc + ch) * HW + colx] = f2bu(acc[i][j][r] + bias);
            }
        }
    }
}

// ============== 64x64 last-two-dims transpose (bf16 -> bf16) ==============
__global__ __launch_bounds__(256) void transpose64_bb(
    const u16* __restrict__ src, u16* __restrict__ dst)
{
    __shared__ u16 t[64][65];
    const size_t s = blockIdx.x;
    const u16* sp = src + s * 4096;
    u16* dp = dst + s * 4096;
    const int tid = threadIdx.x;
    #pragma unroll
    for (int i = 0; i < 16; i++) { int idx = tid + 256 * i; t[idx >> 6][idx & 63] = sp[idx]; }
    __syncthreads();
    #pragma unroll
    for (int i = 0; i < 16; i++) { int idx = tid + 256 * i; dp[idx] = t[idx & 63][idx >> 6]; }
}

// ============== in-place per-slice 64x64 f32 transpose ==============
__global__ __launch_bounds__(256) void transpose64_f32_inplace(float* __restrict__ d)
{
    __shared__ float t[64][65];
    float* p = d + (size_t)blockIdx.x * 4096;
    const int tid = threadIdx.x;
    #pragma unroll
    for (int i = 0; i < 16; i++) { int idx = tid + 256 * i; t[idx >> 6][idx & 63] = p[idx]; }
    __syncthreads();
    #pragma unroll
    for (int i = 0; i < 16; i++) { int idx = tid + 256 * i; p[idx] = t[idx & 63][idx >> 6]; }
}

// ======================= energies =======================
// e layout: (b,h,w,128) fp32. [0:64) = energy_H, [64:128) = energy_W.
__global__ __launch_bounds__(256) void energy_h(
    const u16* __restrict__ qT, const u16* __restrict__ kT, float* __restrict__ e)
{
    __shared__ float Qs[64][68];  // [c][h]
    __shared__ float Ks[64][68];  // [c][H']
    const int w = blockIdx.x, b = blockIdx.y;
    const int tid = threadIdx.x;
    const size_t base = (size_t)b * 64 * HW + (size_t)w * 64;  // qT[b,c,w,h]
    #pragma unroll
    for (int i = 0; i < 16; i++) {
        int idx = tid + 256 * i;
        int c = idx >> 6, x = idx & 63;
        Qs[c][x] = bfu2f(qT[base + (size_t)c * HW + x]);
        Ks[c][x] = bfu2f(kT[base + (size_t)c * HW + x]);
    }
    __syncthreads();
    const int tx = tid & 15, ty = tid >> 4;  // tx -> h, ty -> H'
    float acc[4][4] = {};
    #pragma unroll 8
    for (int c = 0; c < 64; c++) {
        float4 qv = *reinterpret_cast<const float4*>(&Qs[c][tx * 4]);
        float4 kv = *reinterpret_cast<const float4*>(&Ks[c][ty * 4]);
        float a[4] = {qv.x, qv.y, qv.z, qv.w};
        float d[4] = {kv.x, kv.y, kv.z, kv.w};
        #pragma unroll
        for (int i = 0; i < 4; i++)
            #pragma unroll
            for (int j = 0; j < 4; j++) acc[i][j] += a[i] * d[j];
    }
    #pragma unroll
    for (int i = 0; i < 4; i++) {
        float4 v = make_float4(acc[i][0], acc[i][1], acc[i][2], acc[i][3]);
        *reinterpret_cast<float4*>(e + ((size_t)(b * 64 + tx * 4 + i) * 64 + w) * 128 + ty * 4) = v;
    }
}

__global__ __launch_bounds__(256) void energy_w(
    const u16* __restrict__ q, const u16* __restrict__ k, float* __restrict__ e)
{
    __shared__ float Qs[64][68];  // [c][w]
    __shared__ float Ks[64][68];  // [c][W']
    const int h = blockIdx.x, b = blockIdx.y;
    const int tid = threadIdx.x;
    const size_t base = (size_t)b * 64 * HW + (size_t)h * 64;  // q[b,c,h,w]
    #pragma unroll
    for (int i = 0; i < 16; i++) {
        int idx = tid + 256 * i;
        int c = idx >> 6, x = idx & 63;
        Qs[c][x] = bfu2f(q[base + (size_t)c * HW + x]);
        Ks[c][x] = bfu2f(k[base + (size_t)c * HW + x]);
    }
    __syncthreads();
    const int tx = tid & 15, ty = tid >> 4;  // tx -> w, ty -> W'
    float acc[4][4] = {};
    #pragma unroll 8
    for (int c = 0; c < 64; c++) {
        float4 qv = *reinterpret_cast<const float4*>(&Qs[c][tx * 4]);
        float4 kv = *reinterpret_cast<const float4*>(&Ks[c][ty * 4]);
        float a[4] = {qv.x, qv.y, qv.z, qv.w};
        float d[4] = {kv.x, kv.y, kv.z, kv.w};
        #pragma unroll
        for (int i = 0; i < 4; i++)
            #pragma unroll
            for (int j = 0; j < 4; j++) acc[i][j] += a[i] * d[j];
    }
    #pragma unroll
    for (int i = 0; i < 4; i++) {
        float4 v = make_float4(acc[i][0], acc[i][1], acc[i][2], acc[i][3]);
        *reinterpret_cast<float4*>(e + ((size_t)(b * 64 + h) * 64 + tx * 4 + i) * 128 + 64 + ty * 4) = v;
    }
}

// ======================= softmax over 128, in place =======================
__global__ __launch_bounds__(256) void softmax128(float* __restrict__ e)
{
    const int pos = blockIdx.x * 4 + (threadIdx.x >> 6);
    const int l = threadIdx.x & 63;
    float* p = e + (size_t)pos * 128;
    float v0 = p[l], v1 = p[l + 64];
    float m = fmaxf(v0, v1);
    #pragma unroll
    for (int o = 32; o > 0; o >>= 1) m = fmaxf(m, __shfl_xor(m, o, 64));
    float e0 = __expf(v0 - m), e1 = __expf(v1 - m);
    float s = e0 + e1;
    #pragma unroll
    for (int o = 32; o > 0; o >>= 1) s += __shfl_xor(s, o, 64);
    float inv = 1.0f / s;
    p[l] = e0 * inv;
    p[l + 64] = e1 * inv;
}

// ======================= H-term aggregation (coalesced via vT) ============
// outH[b,c,h,w] = sum_H' vT[b,c,w,H'] * att_H[b,h,w,H']; written f32 into
// d_out in (b,c,w,h) order (coalesced over h); transposed in place after.
__global__ __launch_bounds__(256) void agg_h(
    const u16* __restrict__ v2T, const u16* __restrict__ v1T,
    const float* __restrict__ att, float* __restrict__ outp)
{
    __shared__ float As[64][68];  // [H'][h]
    __shared__ float Vs[64][68];  // [H'][c]
    const int ct = blockIdx.x, w = blockIdx.y, b = blockIdx.z;
    const int tid = threadIdx.x;
    #pragma unroll
    for (int i = 0; i < 16; i++) {
        int idx = tid + 256 * i;
        int hh = idx >> 6, hp = idx & 63;
        As[hp][hh] = att[((size_t)(b * 64 + hh) * 64 + w) * 128 + hp];
    }
    const int tx = tid & 15, ty = tid >> 4;  // tx -> h, ty -> c
    const size_t vbase = ((size_t)(b * 512 + ct * 64) * 64 + w) * 64;  // vT[b,c,w,:]
    for (int vs = 0; vs < 2; vs++) {
        const u16* vT = vs ? v1T : v2T;
        __syncthreads();
        #pragma unroll
        for (int i = 0; i < 16; i++) {
            int idx = tid + 256 * i;
            int c = idx >> 6, hp = idx & 63;  // coalesced reads of vT
            Vs[hp][c] = bfu2f(vT[vbase + (size_t)c * 4096 + hp]);
        }
        __syncthreads();
        float acc[4][4] = {};
        #pragma unroll 8
        for (int hp = 0; hp < 64; hp++) {
            float4 vv = *reinterpret_cast<const float4*>(&Vs[hp][ty * 4]);
            float4 aa = *reinterpret_cast<const float4*>(&As[hp][tx * 4]);
            float a[4] = {vv.x, vv.y, vv.z, vv.w};
            float d[4] = {aa.x, aa.y, aa.z, aa.w};
            #pragma unroll
            for (int i = 0; i < 4; i++)
                #pragma unroll
                for (int j = 0; j < 4; j++) acc[i][j] += a[i] * d[j];
        }
        float* po = outp + (size_t)vs * PLANE;
        #pragma unroll
        for (int i = 0; i < 4; i++) {
            float4 y = make_float4(acc[i][0], acc[i][1], acc[i][2], acc[i][3]);
            *reinterpret_cast<float4*>(
                &po[((size_t)(b * 512 + ct * 64 + ty * 4 + i) * 64 + w) * 64 + tx * 4]) = y;
        }
    }
}

// ======================= W-term + epilogue =======================
// outW[b,c,h,w] = sum_W' v[b,c,h,W'] * att_W[b,h,w,W']
// y = g*(partialH + outW) + x, in place in d_out (f32).
__global__ __launch_bounds__(256) void agg_w(
    const u16* __restrict__ v2, const u16* __restrict__ v1,
    const float* __restrict__ att,
    const float* __restrict__ x2, const float* __restrict__ x1,
    const float* __restrict__ gptr, float* __restrict__ outp)
{
    __shared__ float As[64][68];  // [W'][w]
    __shared__ float Vs[64][68];  // [W'][c]
    const int ct = blockIdx.x, h = blockIdx.y, b = blockIdx.z;
    const int tid = threadIdx.x;
    #pragma unroll
    for (int i = 0; i < 16; i++) {
        int idx = tid + 256 * i;
        int ww = idx >> 6, wp = idx & 63;
        As[wp][ww] = att[((size_t)(b * 64 + h) * 64 + ww) * 128 + 64 + wp];
    }
    const float g = gptr[0];
    const int tx = tid & 15, ty = tid >> 4;  // tx -> w, ty -> c
    const size_t vbase = (size_t)(b * 512 + ct * 64) * HW + (size_t)h * 64;
    for (int vs = 0; vs < 2; vs++) {
        const u16* v = vs ? v1 : v2;
        const float* x = vs ? x1 : x2;
        float* po = outp + (size_t)vs * PLANE;
        __syncthreads();
        #pragma unroll
        for (int i = 0; i < 16; i++) {
            int idx = tid + 256 * i;
            int c = idx >> 6, wp = idx & 63;  // coalesced
            Vs[wp][c] = bfu2f(v[vbase + (size_t)c * HW + wp]);
        }
        __syncthreads();
        float acc[4][4] = {};
        #pragma unroll 8
        for (int wp = 0; wp < 64; wp++) {
            float4 vv = *reinterpret_cast<const float4*>(&Vs[wp][ty * 4]);
            float4 aa = *reinterpret_cast<const float4*>(&As[wp][tx * 4]);
            float a[4] = {vv.x, vv.y, vv.z, vv.w};
            float d[4] = {aa.x, aa.y, aa.z, aa.w};
            #pragma unroll
            for (int i = 0; i < 4; i++)
                #pragma unroll
                for (int j = 0; j < 4; j++) acc[i][j] += a[i] * d[j];
        }
        #pragma unroll
        for (int i = 0; i < 4; i++) {
            size_t off = (size_t)(b * 512 + ct * 64 + ty * 4 + i) * HW + (size_t)h * 64 + tx * 4;
            float4 pv = *reinterpret_cast<const float4*>(po + off);
            float4 xv = *reinterpret_cast<const float4*>(x + off);
            float4 y;
            y.x = g * (pv.x + acc[i][0]) + xv.x;
            y.y = g * (pv.y + acc[i][1]) + xv.y;
            y.z = g * (pv.z + acc[i][2]) + xv.z;
            y.w = g * (pv.w + acc[i][3]) + xv.w;
            *reinterpret_cast<float4*>(po + off) = y;
        }
    }
}

// ======================= host =======================
extern "C" void kernel_launch(void* const* d_in, const int* in_sizes, int n_in,
                              void* d_out, int out_size, void* d_ws, size_t ws_size,
                              hipStream_t stream)
{
    (void)in_sizes; (void)n_in; (void)out_size; (void)ws_size;
    const float* x2  = (const float*)d_in[0];
    const float* x1  = (const float*)d_in[1];
    const float* q_w = (const float*)d_in[2];
    const float* q_b = (const float*)d_in[3];
    const float* k_w = (const float*)d_in[4];
    const float* k_b = (const float*)d_in[5];
    const float* v_w = (const float*)d_in[6];
    const float* v_b = (const float*)d_in[7];
    const float* gm  = (const float*)d_in[8];

    // ws (MiB): q 0-4 | k 4-8 | qT 8-12 | kT 12-16 | e(f32) 16-32
    //           v2 32-64 | v1 64-96 | v2T 96-128 | v1T 128-160  (160 MiB)
    char* ws = (char*)d_ws;
    u16*   q   = (u16*)(ws);
    u16*   k   = (u16*)(ws + ((size_t)4   << 20));
    u16*   qT  = (u16*)(ws + ((size_t)8   << 20));
    u16*   kT  = (u16*)(ws + ((size_t)12  << 20));
    float* e   = (float*)(ws + ((size_t)16 << 20));
    u16*   v2  = (u16*)(ws + ((size_t)32  << 20));
    u16*   v1  = (u16*)(ws + ((size_t)64  << 20));
    u16*   v2T = (u16*)(ws + ((size_t)96  << 20));
    u16*   v1T = (u16*)(ws + ((size_t)128 << 20));
    float* out = (float*)d_out;

    dim3 blk(256);
    // fused q/k/v2 projection from x2 (M=640), v1 from x1 (M=512)
    proj_mfma<<<dim3(256, 5), blk, 0, stream>>>(x2, q_w, q_b, 64, k_w, k_b, 64,
                                                v_w, v_b, q, k, v2, 64, 64, 512);
    proj_mfma<<<dim3(256, 4), blk, 0, stream>>>(x1, v_w, v_b, 0, v_w, v_b, 0,
                                                v_w, v_b, q, k, v1, 64, 64, 512);
    transpose64_bb<<<1024, blk, 0, stream>>>(q, qT);    // q+k -> qT+kT
    transpose64_bb<<<8192, blk, 0, stream>>>(v2, v2T);  // v2+v1 -> v2T+v1T
    energy_h<<<dim3(64, 8), blk, 0, stream>>>(qT, kT, e);
    energy_w<<<dim3(64, 8), blk, 0, stream>>>(q, k, e);
    softmax128<<<8192, blk, 0, stream>>>(e);
    agg_h<<<dim3(8, 64, 8), blk, 0, stream>>>(v2T, v1T, e, out);       // (b,c,w,h) f32
    transpose64_f32_inplace<<<8192, blk, 0, stream>>>(out);            // -> (b,c,h,w)
    agg_w<<<dim3(8, 64, 8), blk, 0, stream>>>(v2, v1, e, x2, x1, gm, out);
}